// Round 9
// baseline (152.184 us; speedup 1.0000x reference)
//
#include <hip/hip_runtime.h>

#define N_NODES 10000
#define N_EDGES 640000
#define IN_DIM  128
#define HID_DIM 256
#define OUT_DIM 128

#define MAXDEG  128   // deg ~ Binom(640k,1e-4): mean 64, P(>128) ~ 1e-11
#define ZROW    10000 // sentinel node index -> all-zero feature row

#define NWIN      20
#define WIN_NODES 500              // 20 * 500 = 10000
#define NPART     8                // edge partitions per window
#define EDGES_PER_PART (N_EDGES / NPART)     // 80,000
#define CAP       48               // per-(node,part) cap: lambda=8, P(>48)~0
#define K1_THREADS 512

typedef __attribute__((ext_vector_type(8))) short short8;
typedef __attribute__((ext_vector_type(4))) float float4v;
typedef unsigned short ushort_t;
typedef unsigned int uint_t;

__device__ inline ushort_t f2bf(float f) {
    uint_t u = __float_as_uint(f);
    u += 0x7fffu + ((u >> 16) & 1u);
    return (ushort_t)(u >> 16);
}
__device__ inline float bf_lo(uint_t u) { return __uint_as_float(u << 16); }
__device__ inline float bf_hi(uint_t u) { return __uint_as_float(u & 0xffff0000u); }

#define PREP_X   (N_NODES * IN_DIM)
#define PREP_W1  (HID_DIM * (2 * IN_DIM))
#define PREP_W2  (OUT_DIM * HID_DIM)
#define PREP_TOTAL (PREP_X + PREP_W1 + 2 * PREP_W2)   // 1,411,072

#define BIN_BLOCKS (NWIN * NPART)            // 160
#define PREP_BLOCKS 1024
#define PREP_STRIDE (PREP_BLOCKS * K1_THREADS)

// ---------------------------------------------------------------------------
// K1: (window x edge-part) LDS binning + global slot reservation + prep.
// SINGLE change vs round 8 (146.2 us): NWIN 80 -> 20 (WIN_NODES 500, 48 KB
// LDS slots). Per-block scan work unchanged (80K edges); aggregate edge
// re-read traffic drops 410 -> 102 MB (~9-10 us of L2 stream). R7 proved
// this config correct; R7's regression was the simultaneous ILP-8 change
// (VGPR/occupancy), reverted in R8.
// ---------------------------------------------------------------------------
__global__ void __launch_bounds__(K1_THREADS)
bin_prep(const float* __restrict__ x, const int* __restrict__ ei,
         const float* __restrict__ W1_l, const float* __restrict__ W1_r,
         const float* __restrict__ W2_l, const float* __restrict__ W2_r,
         ushort_t* __restrict__ xb,  ushort_t* __restrict__ w1t,
         ushort_t* __restrict__ w2tl, ushort_t* __restrict__ w2tr,
         int* __restrict__ cnt, ushort_t* __restrict__ esrc2,
         ushort_t* __restrict__ Pb) {
    __shared__ alignas(16) ushort_t slots[WIN_NODES * CAP];   // 48,000 B
    __shared__ int lcnt[WIN_NODES];
    __shared__ int lbase[WIN_NODES];
    const int bid = blockIdx.x;
    const int tid = threadIdx.x;

    if (bid < BIN_BLOCKS) {
        const int win  = bid >> 3;           // 0..19
        const int part = bid & (NPART - 1);  // 0..7
        const int lo   = win * WIN_NODES;
        if (tid < WIN_NODES) lcnt[tid] = 0;
        __syncthreads();

        const int4* s4 = (const int4*)ei + part * (EDGES_PER_PART / 4);
        const int4* d4 = (const int4*)(ei + N_EDGES) + part * (EDGES_PER_PART / 4);
        for (int t = tid; t < EDGES_PER_PART / 4; t += K1_THREADS) {
            int4 d = d4[t];
            int4 s = s4[t];                  // unconditional: overlaps with d load
            int a, p;
            a = d.x - lo; if ((unsigned)a < (unsigned)WIN_NODES) {
                p = atomicAdd(&lcnt[a], 1); if (p < CAP) slots[a * CAP + p] = (ushort_t)s.x;
            }
            a = d.y - lo; if ((unsigned)a < (unsigned)WIN_NODES) {
                p = atomicAdd(&lcnt[a], 1); if (p < CAP) slots[a * CAP + p] = (ushort_t)s.y;
            }
            a = d.z - lo; if ((unsigned)a < (unsigned)WIN_NODES) {
                p = atomicAdd(&lcnt[a], 1); if (p < CAP) slots[a * CAP + p] = (ushort_t)s.z;
            }
            a = d.w - lo; if ((unsigned)a < (unsigned)WIN_NODES) {
                p = atomicAdd(&lcnt[a], 1); if (p < CAP) slots[a * CAP + p] = (ushort_t)s.w;
            }
        }
        __syncthreads();
        // reserve slot ranges in the global per-node lists
        if (tid < WIN_NODES)
            lbase[tid] = atomicAdd(&cnt[lo + tid], min(lcnt[tid], CAP));
        __syncthreads();
        // copy out: thread per (node, slot); contiguous ~16 B runs per node
        for (int i = tid; i < WIN_NODES * CAP; i += K1_THREADS) {
            int node = i / CAP, slot = i - node * CAP;
            if (slot < min(lcnt[node], CAP)) {
                int pos = lbase[node] + slot;
                if (pos < MAXDEG) esrc2[(lo + node) * MAXDEG + pos] = slots[i];
            }
        }
        return;
    }

    // ---- prep blocks ----
    const int gtid = (bid - BIN_BLOCKS) * K1_THREADS + tid;
    for (int i = gtid; i < PREP_TOTAL; i += PREP_STRIDE) {
        if (i < PREP_X) {
            xb[i] = f2bf(x[i]);
        } else if (i < PREP_X + PREP_W1) {
            int j = i - PREP_X;
            int n = j >> 8, k = j & 255;          // w1t[n][k], n in [0,256)
            float v = (k < 128) ? W1_l[k * HID_DIM + n] : W1_r[(k - 128) * HID_DIM + n];
            w1t[j] = f2bf(v);
        } else if (i < PREP_X + PREP_W1 + PREP_W2) {
            int j = i - (PREP_X + PREP_W1);
            int n = j >> 8, k = j & 255;
            w2tl[j] = f2bf(W2_l[k * OUT_DIM + n]);
        } else {
            int j = i - (PREP_X + PREP_W1 + PREP_W2);
            int n = j >> 8, k = j & 255;
            w2tr[j] = f2bf(W2_r[k * OUT_DIM + n]);
        }
    }
    // zero rows for gather sentinel padding (ZROW = N_NODES)
    if (gtid < 128) {
        xb[ZROW * IN_DIM + gtid] = 0;
        Pb[ZROW * OUT_DIM + gtid] = 0;
    }
}

// ---------------------------------------------------------------------------
// K2: fused gather-mean + GEMM layers 1+2 per 16-node tile. 625 blocks x 512.
//   gather: wave w gathers nodes wrow+2w, wrow+2w+1 into swizzled LDS aggl.
//           idx rows staged in LDS, padded to x16 with ZROW sentinels;
//           4-deep tail-free main loop.
//   phase 1: wave w computes h cols [32w,32w+32) = relu([agg|x]@W1+b1) -> hl.
//   phase 2: waves 0-3 -> Pb = h@W2_l (bf16); waves 4-7 -> Rf = h@W2_r (f32).
// Swizzles (G4): byte ^= ((row&7)<<4), same involution write & read.
// A-frag: A[m=lane&15][k=q*8+j]; B-frag: Wt[n][k]; C/D: col=lane&15,
// row=q*4+reg (m89-verified layouts).
// ---------------------------------------------------------------------------
__global__ void __launch_bounds__(512)
gather_gemm(const ushort_t* __restrict__ xb, const int* __restrict__ cnt,
            const ushort_t* __restrict__ esrc2, const ushort_t* __restrict__ w1t,
            const float* __restrict__ b1, const ushort_t* __restrict__ w2tl,
            const ushort_t* __restrict__ w2tr,
            ushort_t* __restrict__ Pb, float* __restrict__ Rf) {
    __shared__ alignas(16) ushort_t aggl[16 * 128];       // 4 KB, swizzled
    __shared__ alignas(16) ushort_t hl[16 * 256];         // 8 KB, swizzled
    __shared__ alignas(16) ushort_t sidx[8][2][MAXDEG];   // 4 KB idx staging
    const int wrow = blockIdx.x * 16;
    const int w = threadIdx.x >> 6;               // wave 0..7
    const int lane = threadIdx.x & 63;

    // stage this wave's two idx rows (2 x 256 B) via uint4
    if (lane < 32) {
        int nd = lane >> 4, i = lane & 15;
        ((uint4*)sidx[w][nd])[i] =
            ((const uint4*)(esrc2 + (wrow + w * 2 + nd) * MAXDEG))[i];
    }
    // degrees + pad-to-16 with ZROW sentinels (<=15 entries per node)
    const int d0 = min(cnt[wrow + w * 2],     MAXDEG);
    const int d1 = min(cnt[wrow + w * 2 + 1], MAXDEG);
    const int p0 = (d0 + 15) & ~15;
    const int p1 = (d1 + 15) & ~15;
    if (lane < p0 - d0) sidx[w][0][d0 + lane] = (ushort_t)ZROW;
    {
        int l2 = lane - 32;
        if (l2 >= 0 && l2 < p1 - d1) sidx[w][1][d1 + l2] = (ushort_t)ZROW;
    }

    // ---- gather 2 nodes per wave into aggl (4-deep, tail-free) ----
    {
        const uint4* f = (const uint4*)xb;        // 16 uint4 per 256 B row
        const int g = lane >> 4;                  // slot group 0..3
        const int c = lane & 15;                  // 16 B column
        for (int i = 0; i < 2; ++i) {
            const int row = w * 2 + i;
            const int deg = i ? d1 : d0;
            const int pad = i ? p1 : p0;
            const ushort_t* idx = sidx[w][i];
            float a0=0,a1=0,a2=0,a3=0,a4=0,a5=0,a6=0,a7=0;
            for (int e = g; e < pad; e += 16) {   // 4 rows in flight per group
                uint4 u0 = f[(int)idx[e]      * 16 + c];
                uint4 u1 = f[(int)idx[e + 4]  * 16 + c];
                uint4 u2 = f[(int)idx[e + 8]  * 16 + c];
                uint4 u3 = f[(int)idx[e + 12] * 16 + c];
                a0 += bf_lo(u0.x) + bf_lo(u1.x) + bf_lo(u2.x) + bf_lo(u3.x);
                a1 += bf_hi(u0.x) + bf_hi(u1.x) + bf_hi(u2.x) + bf_hi(u3.x);
                a2 += bf_lo(u0.y) + bf_lo(u1.y) + bf_lo(u2.y) + bf_lo(u3.y);
                a3 += bf_hi(u0.y) + bf_hi(u1.y) + bf_hi(u2.y) + bf_hi(u3.y);
                a4 += bf_lo(u0.z) + bf_lo(u1.z) + bf_lo(u2.z) + bf_lo(u3.z);
                a5 += bf_hi(u0.z) + bf_hi(u1.z) + bf_hi(u2.z) + bf_hi(u3.z);
                a6 += bf_lo(u0.w) + bf_lo(u1.w) + bf_lo(u2.w) + bf_lo(u3.w);
                a7 += bf_hi(u0.w) + bf_hi(u1.w) + bf_hi(u2.w) + bf_hi(u3.w);
            }
#pragma unroll
            for (int off = 32; off >= 16; off >>= 1) {
                a0 += __shfl_down(a0, off); a1 += __shfl_down(a1, off);
                a2 += __shfl_down(a2, off); a3 += __shfl_down(a3, off);
                a4 += __shfl_down(a4, off); a5 += __shfl_down(a5, off);
                a6 += __shfl_down(a6, off); a7 += __shfl_down(a7, off);
            }
            if (g == 0) {
                const float dinv = (deg > 0) ? 1.0f / (float)deg : 0.0f;
                uint4 o;
                o.x = (uint_t)f2bf(a0 * dinv) | ((uint_t)f2bf(a1 * dinv) << 16);
                o.y = (uint_t)f2bf(a2 * dinv) | ((uint_t)f2bf(a3 * dinv) << 16);
                o.z = (uint_t)f2bf(a4 * dinv) | ((uint_t)f2bf(a5 * dinv) << 16);
                o.w = (uint_t)f2bf(a6 * dinv) | ((uint_t)f2bf(a7 * dinv) << 16);
                int byte = (row * 256 + c * 16) ^ ((row & 7) << 4);
                *(uint4*)((char*)aggl + byte) = o;
            }
        }
    }
    __syncthreads();

    // ---- phase 1: h cols [32w, 32w+32) ----
    const int m = lane & 15, q = lane >> 4;
    {
        float4v acc[2];
#pragma unroll
        for (int t = 0; t < 2; ++t) acc[t] = (float4v){0.f, 0.f, 0.f, 0.f};
        const ushort_t* arow_x = xb + (wrow + m) * IN_DIM + q * 8;
        const ushort_t* bbase1 = w1t + (w * 32 + m) * 256 + q * 8;
#pragma unroll
        for (int s = 0; s < 8; ++s) {
            short8 a;
            if (s < 4) {
                int byte = (m * 256 + q * 16 + s * 64) ^ ((m & 7) << 4);
                a = *(const short8*)((const char*)aggl + byte);
            } else {
                a = *(const short8*)(arow_x + (s - 4) * 32);
            }
#pragma unroll
            for (int t = 0; t < 2; ++t) {
                short8 b = *(const short8*)(bbase1 + (t * 16) * 256 + s * 32);
                acc[t] = __builtin_amdgcn_mfma_f32_16x16x32_bf16(a, b, acc[t], 0, 0, 0);
            }
        }
#pragma unroll
        for (int t = 0; t < 2; ++t) {
            int col = w * 32 + t * 16 + m;
            float bv = b1[col];
#pragma unroll
            for (int r = 0; r < 4; ++r) {
                int row = q * 4 + r;
                float v = fmaxf(acc[t][r] + bv, 0.0f);
                int byte = (row * 512 + col * 2) ^ ((row & 7) << 4);
                *(ushort_t*)((char*)hl + byte) = f2bf(v);
            }
        }
    }
    __syncthreads();

    // ---- phase 2: waves 0-3 -> P, waves 4-7 -> R ----
    {
        const int isP = (w < 4);
        const int cb = (w & 3) * 32;
        const ushort_t* wt = isP ? w2tl : w2tr;
        float4v acc2[2];
#pragma unroll
        for (int t = 0; t < 2; ++t) acc2[t] = (float4v){0.f, 0.f, 0.f, 0.f};
        const ushort_t* bbase2 = wt + (cb + m) * 256 + q * 8;
#pragma unroll
        for (int s = 0; s < 8; ++s) {
            int byte = (m * 512 + q * 16 + s * 64) ^ ((m & 7) << 4);
            short8 a = *(const short8*)((const char*)hl + byte);
#pragma unroll
            for (int t = 0; t < 2; ++t) {
                short8 b = *(const short8*)(bbase2 + (t * 16) * 256 + s * 32);
                acc2[t] = __builtin_amdgcn_mfma_f32_16x16x32_bf16(a, b, acc2[t], 0, 0, 0);
            }
        }
        if (isP) {
#pragma unroll
            for (int t = 0; t < 2; ++t) {
                int col = cb + t * 16 + m;
#pragma unroll
                for (int r = 0; r < 4; ++r)
                    Pb[(wrow + q * 4 + r) * OUT_DIM + col] = f2bf(acc2[t][r]);
            }
        } else {
#pragma unroll
            for (int t = 0; t < 2; ++t) {
                int col = cb + t * 16 + m;
#pragma unroll
                for (int r = 0; r < 4; ++r)
                    Rf[(wrow + q * 4 + r) * OUT_DIM + col] = acc2[t][r];
            }
        }
    }
}

// ---------------------------------------------------------------------------
// K3: final gather + epilogue: out[n][:] = mean_e P[esrc[e]][:] + R[n][:] + b2
// One 64-thread block per node; idx staged in LDS, padded to x16 with ZROW
// sentinels; 4-deep tail-free main loop.
// ---------------------------------------------------------------------------
__global__ void gather_final(const ushort_t* __restrict__ Pb,
                             const int* __restrict__ degp,
                             const ushort_t* __restrict__ esrc2,
                             const float* __restrict__ Rf,
                             const float* __restrict__ b2,
                             float* __restrict__ out) {
    __shared__ alignas(16) ushort_t sidx[MAXDEG];
    const uint4* f = (const uint4*)Pb;            // 16 uint4 per row
    const int n = blockIdx.x;
    const int g = threadIdx.x >> 4;
    const int c = threadIdx.x & 15;
    const int deg = min(degp[n], MAXDEG);
    const int pad = (deg + 15) & ~15;

    if (threadIdx.x < 16)
        ((uint4*)sidx)[threadIdx.x] = ((const uint4*)(esrc2 + n * MAXDEG))[threadIdx.x];
    __syncthreads();
    if (threadIdx.x < pad - deg) sidx[deg + threadIdx.x] = (ushort_t)ZROW;
    __syncthreads();

    float a0=0,a1=0,a2=0,a3=0,a4=0,a5=0,a6=0,a7=0;
    for (int e = g; e < pad; e += 16) {           // 4 rows in flight, no tail
        uint4 u0 = f[(int)sidx[e]      * 16 + c];
        uint4 u1 = f[(int)sidx[e + 4]  * 16 + c];
        uint4 u2 = f[(int)sidx[e + 8]  * 16 + c];
        uint4 u3 = f[(int)sidx[e + 12] * 16 + c];
        a0 += bf_lo(u0.x) + bf_lo(u1.x) + bf_lo(u2.x) + bf_lo(u3.x);
        a1 += bf_hi(u0.x) + bf_hi(u1.x) + bf_hi(u2.x) + bf_hi(u3.x);
        a2 += bf_lo(u0.y) + bf_lo(u1.y) + bf_lo(u2.y) + bf_lo(u3.y);
        a3 += bf_hi(u0.y) + bf_hi(u1.y) + bf_hi(u2.y) + bf_hi(u3.y);
        a4 += bf_lo(u0.z) + bf_lo(u1.z) + bf_lo(u2.z) + bf_lo(u3.z);
        a5 += bf_hi(u0.z) + bf_hi(u1.z) + bf_hi(u2.z) + bf_hi(u3.z);
        a6 += bf_lo(u0.w) + bf_lo(u1.w) + bf_lo(u2.w) + bf_lo(u3.w);
        a7 += bf_hi(u0.w) + bf_hi(u1.w) + bf_hi(u2.w) + bf_hi(u3.w);
    }
#pragma unroll
    for (int off = 32; off >= 16; off >>= 1) {
        a0 += __shfl_down(a0, off); a1 += __shfl_down(a1, off);
        a2 += __shfl_down(a2, off); a3 += __shfl_down(a3, off);
        a4 += __shfl_down(a4, off); a5 += __shfl_down(a5, off);
        a6 += __shfl_down(a6, off); a7 += __shfl_down(a7, off);
    }
    if (g == 0) {
        const float dinv = (deg > 0) ? 1.0f / (float)deg : 0.0f;
        const int base = n * OUT_DIM + c * 8;
        float4 r0 = *(const float4*)(Rf + base);
        float4 r1 = *(const float4*)(Rf + base + 4);
        float4 o0, o1;
        o0.x = a0 * dinv + r0.x + b2[c * 8 + 0];
        o0.y = a1 * dinv + r0.y + b2[c * 8 + 1];
        o0.z = a2 * dinv + r0.z + b2[c * 8 + 2];
        o0.w = a3 * dinv + r0.w + b2[c * 8 + 3];
        o1.x = a4 * dinv + r1.x + b2[c * 8 + 4];
        o1.y = a5 * dinv + r1.y + b2[c * 8 + 5];
        o1.z = a6 * dinv + r1.z + b2[c * 8 + 6];
        o1.w = a7 * dinv + r1.w + b2[c * 8 + 7];
        *(float4*)(out + base)     = o0;
        *(float4*)(out + base + 4) = o1;
    }
}

// ---------------------------------------------------------------------------
// Launch: memset (cnt, needed for atomic slot reservation) + 3 kernels.
// ---------------------------------------------------------------------------
extern "C" void kernel_launch(void* const* d_in, const int* in_sizes, int n_in,
                              void* d_out, int out_size, void* d_ws, size_t ws_size,
                              hipStream_t stream) {
    const float* x    = (const float*)d_in[0];
    const int*   ei   = (const int*)  d_in[1];
    const float* W1_l = (const float*)d_in[2];
    const float* b1   = (const float*)d_in[3];
    const float* W1_r = (const float*)d_in[4];
    const float* W2_l = (const float*)d_in[5];
    const float* b2   = (const float*)d_in[6];
    const float* W2_r = (const float*)d_in[7];
    float* out = (float*)d_out;

    // ---- workspace layout (byte offsets, all 16 B-aligned) ----
    // xb and Pb carry one extra zero row (ZROW = 10000) for sentinel padding.
    char* w = (char*)d_ws;
    int*      cnt   = (int*)     (w + 0);          //    40,000 B (reserve 64 KB)
    ushort_t* esrc2 = (ushort_t*)(w + 65536);      // 2,560,000 B
    ushort_t* xb    = (ushort_t*)(w + 2625536);    // 2,560,256 B (10001 rows)
    ushort_t* Pb    = (ushort_t*)(w + 5185792);    // 2,560,256 B (10001 rows)
    ushort_t* w1t   = (ushort_t*)(w + 7746048);    //   131,072 B
    ushort_t* w2tl  = (ushort_t*)(w + 7877120);    //    65,536 B
    ushort_t* w2tr  = (ushort_t*)(w + 7942656);    //    65,536 B
    float*    Rf    = (float*)   (w + 8008192);    // 5,120,000 B -> ends 13,128,192

    hipMemsetAsync(cnt, 0, N_NODES * sizeof(int), stream);

    bin_prep<<<BIN_BLOCKS + PREP_BLOCKS, K1_THREADS, 0, stream>>>(
        x, ei, W1_l, W1_r, W2_l, W2_r, xb, w1t, w2tl, w2tr, cnt, esrc2, Pb);
    gather_gemm<<<625, 512, 0, stream>>>(xb, cnt, esrc2, w1t, b1, w2tl, w2tr, Pb, Rf);
    gather_final<<<N_NODES, 64, 0, stream>>>(Pb, cnt, esrc2, Rf, b2, out);
}

// Round 10
// 145.224 us; speedup vs baseline: 1.0479x; 1.0479x over previous
//
#include <hip/hip_runtime.h>

#define N_NODES 10000
#define N_EDGES 640000
#define IN_DIM  128
#define HID_DIM 256
#define OUT_DIM 128

#define MAXDEG  128   // deg ~ Binom(640k,1e-4): mean 64, P(>128) ~ 1e-11
#define ZROW    10000 // sentinel node index -> all-zero feature row

#define NWIN      80
#define WIN_NODES 125              // 80 * 125 = 10000
#define NPART     8                // edge partitions per window
#define EDGES_PER_PART (N_EDGES / NPART)     // 80,000
#define CAP       48               // per-(node,part) cap: lambda=8, P(>48)~0
#define K1_THREADS 512

typedef __attribute__((ext_vector_type(8))) short short8;
typedef __attribute__((ext_vector_type(4))) float float4v;
typedef unsigned short ushort_t;
typedef unsigned int uint_t;

__device__ inline ushort_t f2bf(float f) {
    uint_t u = __float_as_uint(f);
    u += 0x7fffu + ((u >> 16) & 1u);
    return (ushort_t)(u >> 16);
}
__device__ inline float bf_lo(uint_t u) { return __uint_as_float(u << 16); }
__device__ inline float bf_hi(uint_t u) { return __uint_as_float(u & 0xffff0000u); }

#define PREP_X   (N_NODES * IN_DIM)
#define PREP_W1  (HID_DIM * (2 * IN_DIM))
#define PREP_W2  (OUT_DIM * HID_DIM)
#define PREP_TOTAL (PREP_X + PREP_W1 + 2 * PREP_W2)   // 1,411,072

#define BIN_BLOCKS (NWIN * NPART)            // 640  (measured-best config)
#define PREP_BLOCKS 1024
#define PREP_STRIDE (PREP_BLOCKS * K1_THREADS)

// ---------------------------------------------------------------------------
// K1: (window x edge-part) LDS binning + global slot reservation + prep.
// FINAL config = round-8 measured best (146.2 us; R6 twin at 144.4).
// Isolated A/B history: NWIN=20 (fewer, fatter bin blocks) = +6 us (R9:
// 82K-thread bin phase under-fills the machine); gather ILP-8 = +14 us (R7:
// VGPR/occupancy); sentinel padding = neutral (R8). Write-amp fix (LDS
// binning + dense-ish runs) = the big K1 win vs R4's 33 MB scattered-store
// writeback.
// ---------------------------------------------------------------------------
__global__ void __launch_bounds__(K1_THREADS)
bin_prep(const float* __restrict__ x, const int* __restrict__ ei,
         const float* __restrict__ W1_l, const float* __restrict__ W1_r,
         const float* __restrict__ W2_l, const float* __restrict__ W2_r,
         ushort_t* __restrict__ xb,  ushort_t* __restrict__ w1t,
         ushort_t* __restrict__ w2tl, ushort_t* __restrict__ w2tr,
         int* __restrict__ cnt, ushort_t* __restrict__ esrc2,
         ushort_t* __restrict__ Pb) {
    __shared__ alignas(16) ushort_t slots[WIN_NODES * CAP];   // 12,000 B
    __shared__ int lcnt[WIN_NODES];
    __shared__ int lbase[WIN_NODES];
    const int bid = blockIdx.x;
    const int tid = threadIdx.x;

    if (bid < BIN_BLOCKS) {
        const int win  = bid >> 3;           // 0..79
        const int part = bid & (NPART - 1);  // 0..7
        const int lo   = win * WIN_NODES;
        if (tid < WIN_NODES) lcnt[tid] = 0;
        __syncthreads();

        const int4* s4 = (const int4*)ei + part * (EDGES_PER_PART / 4);
        const int4* d4 = (const int4*)(ei + N_EDGES) + part * (EDGES_PER_PART / 4);
        for (int t = tid; t < EDGES_PER_PART / 4; t += K1_THREADS) {
            int4 d = d4[t];
            int4 s = s4[t];                  // unconditional: overlaps with d load
            int a, p;
            a = d.x - lo; if ((unsigned)a < (unsigned)WIN_NODES) {
                p = atomicAdd(&lcnt[a], 1); if (p < CAP) slots[a * CAP + p] = (ushort_t)s.x;
            }
            a = d.y - lo; if ((unsigned)a < (unsigned)WIN_NODES) {
                p = atomicAdd(&lcnt[a], 1); if (p < CAP) slots[a * CAP + p] = (ushort_t)s.y;
            }
            a = d.z - lo; if ((unsigned)a < (unsigned)WIN_NODES) {
                p = atomicAdd(&lcnt[a], 1); if (p < CAP) slots[a * CAP + p] = (ushort_t)s.z;
            }
            a = d.w - lo; if ((unsigned)a < (unsigned)WIN_NODES) {
                p = atomicAdd(&lcnt[a], 1); if (p < CAP) slots[a * CAP + p] = (ushort_t)s.w;
            }
        }
        __syncthreads();
        // reserve slot ranges in the global per-node lists
        if (tid < WIN_NODES)
            lbase[tid] = atomicAdd(&cnt[lo + tid], min(lcnt[tid], CAP));
        __syncthreads();
        // copy out: thread per (node, slot); contiguous ~16 B runs per node
        for (int i = tid; i < WIN_NODES * CAP; i += K1_THREADS) {
            int node = i / CAP, slot = i - node * CAP;
            if (slot < min(lcnt[node], CAP)) {
                int pos = lbase[node] + slot;
                if (pos < MAXDEG) esrc2[(lo + node) * MAXDEG + pos] = slots[i];
            }
        }
        return;
    }

    // ---- prep blocks ----
    const int gtid = (bid - BIN_BLOCKS) * K1_THREADS + tid;
    for (int i = gtid; i < PREP_TOTAL; i += PREP_STRIDE) {
        if (i < PREP_X) {
            xb[i] = f2bf(x[i]);
        } else if (i < PREP_X + PREP_W1) {
            int j = i - PREP_X;
            int n = j >> 8, k = j & 255;          // w1t[n][k], n in [0,256)
            float v = (k < 128) ? W1_l[k * HID_DIM + n] : W1_r[(k - 128) * HID_DIM + n];
            w1t[j] = f2bf(v);
        } else if (i < PREP_X + PREP_W1 + PREP_W2) {
            int j = i - (PREP_X + PREP_W1);
            int n = j >> 8, k = j & 255;
            w2tl[j] = f2bf(W2_l[k * OUT_DIM + n]);
        } else {
            int j = i - (PREP_X + PREP_W1 + PREP_W2);
            int n = j >> 8, k = j & 255;
            w2tr[j] = f2bf(W2_r[k * OUT_DIM + n]);
        }
    }
    // zero rows for gather sentinel padding (ZROW = N_NODES)
    if (gtid < 128) {
        xb[ZROW * IN_DIM + gtid] = 0;
        Pb[ZROW * OUT_DIM + gtid] = 0;
    }
}

// ---------------------------------------------------------------------------
// K2: fused gather-mean + GEMM layers 1+2 per 16-node tile. 625 blocks x 512.
//   gather: wave w gathers nodes wrow+2w, wrow+2w+1 into swizzled LDS aggl.
//           idx rows staged in LDS, padded to x16 with ZROW sentinels;
//           4-deep tail-free main loop (ILP-8 regresses: VGPR/occupancy, R7).
//   phase 1: wave w computes h cols [32w,32w+32) = relu([agg|x]@W1+b1) -> hl.
//   phase 2: waves 0-3 -> Pb = h@W2_l (bf16); waves 4-7 -> Rf = h@W2_r (f32).
// Swizzles (G4): byte ^= ((row&7)<<4), same involution write & read.
// A-frag: A[m=lane&15][k=q*8+j]; B-frag: Wt[n][k]; C/D: col=lane&15,
// row=q*4+reg (m89-verified layouts).
// ---------------------------------------------------------------------------
__global__ void __launch_bounds__(512)
gather_gemm(const ushort_t* __restrict__ xb, const int* __restrict__ cnt,
            const ushort_t* __restrict__ esrc2, const ushort_t* __restrict__ w1t,
            const float* __restrict__ b1, const ushort_t* __restrict__ w2tl,
            const ushort_t* __restrict__ w2tr,
            ushort_t* __restrict__ Pb, float* __restrict__ Rf) {
    __shared__ alignas(16) ushort_t aggl[16 * 128];       // 4 KB, swizzled
    __shared__ alignas(16) ushort_t hl[16 * 256];         // 8 KB, swizzled
    __shared__ alignas(16) ushort_t sidx[8][2][MAXDEG];   // 4 KB idx staging
    const int wrow = blockIdx.x * 16;
    const int w = threadIdx.x >> 6;               // wave 0..7
    const int lane = threadIdx.x & 63;

    // stage this wave's two idx rows (2 x 256 B) via uint4
    if (lane < 32) {
        int nd = lane >> 4, i = lane & 15;
        ((uint4*)sidx[w][nd])[i] =
            ((const uint4*)(esrc2 + (wrow + w * 2 + nd) * MAXDEG))[i];
    }
    // degrees + pad-to-16 with ZROW sentinels (<=15 entries per node)
    const int d0 = min(cnt[wrow + w * 2],     MAXDEG);
    const int d1 = min(cnt[wrow + w * 2 + 1], MAXDEG);
    const int p0 = (d0 + 15) & ~15;
    const int p1 = (d1 + 15) & ~15;
    if (lane < p0 - d0) sidx[w][0][d0 + lane] = (ushort_t)ZROW;
    {
        int l2 = lane - 32;
        if (l2 >= 0 && l2 < p1 - d1) sidx[w][1][d1 + l2] = (ushort_t)ZROW;
    }

    // ---- gather 2 nodes per wave into aggl (4-deep, tail-free) ----
    {
        const uint4* f = (const uint4*)xb;        // 16 uint4 per 256 B row
        const int g = lane >> 4;                  // slot group 0..3
        const int c = lane & 15;                  // 16 B column
        for (int i = 0; i < 2; ++i) {
            const int row = w * 2 + i;
            const int deg = i ? d1 : d0;
            const int pad = i ? p1 : p0;
            const ushort_t* idx = sidx[w][i];
            float a0=0,a1=0,a2=0,a3=0,a4=0,a5=0,a6=0,a7=0;
            for (int e = g; e < pad; e += 16) {   // 4 rows in flight per group
                uint4 u0 = f[(int)idx[e]      * 16 + c];
                uint4 u1 = f[(int)idx[e + 4]  * 16 + c];
                uint4 u2 = f[(int)idx[e + 8]  * 16 + c];
                uint4 u3 = f[(int)idx[e + 12] * 16 + c];
                a0 += bf_lo(u0.x) + bf_lo(u1.x) + bf_lo(u2.x) + bf_lo(u3.x);
                a1 += bf_hi(u0.x) + bf_hi(u1.x) + bf_hi(u2.x) + bf_hi(u3.x);
                a2 += bf_lo(u0.y) + bf_lo(u1.y) + bf_lo(u2.y) + bf_lo(u3.y);
                a3 += bf_hi(u0.y) + bf_hi(u1.y) + bf_hi(u2.y) + bf_hi(u3.y);
                a4 += bf_lo(u0.z) + bf_lo(u1.z) + bf_lo(u2.z) + bf_lo(u3.z);
                a5 += bf_hi(u0.z) + bf_hi(u1.z) + bf_hi(u2.z) + bf_hi(u3.z);
                a6 += bf_lo(u0.w) + bf_lo(u1.w) + bf_lo(u2.w) + bf_lo(u3.w);
                a7 += bf_hi(u0.w) + bf_hi(u1.w) + bf_hi(u2.w) + bf_hi(u3.w);
            }
#pragma unroll
            for (int off = 32; off >= 16; off >>= 1) {
                a0 += __shfl_down(a0, off); a1 += __shfl_down(a1, off);
                a2 += __shfl_down(a2, off); a3 += __shfl_down(a3, off);
                a4 += __shfl_down(a4, off); a5 += __shfl_down(a5, off);
                a6 += __shfl_down(a6, off); a7 += __shfl_down(a7, off);
            }
            if (g == 0) {
                const float dinv = (deg > 0) ? 1.0f / (float)deg : 0.0f;
                uint4 o;
                o.x = (uint_t)f2bf(a0 * dinv) | ((uint_t)f2bf(a1 * dinv) << 16);
                o.y = (uint_t)f2bf(a2 * dinv) | ((uint_t)f2bf(a3 * dinv) << 16);
                o.z = (uint_t)f2bf(a4 * dinv) | ((uint_t)f2bf(a5 * dinv) << 16);
                o.w = (uint_t)f2bf(a6 * dinv) | ((uint_t)f2bf(a7 * dinv) << 16);
                int byte = (row * 256 + c * 16) ^ ((row & 7) << 4);
                *(uint4*)((char*)aggl + byte) = o;
            }
        }
    }
    __syncthreads();

    // ---- phase 1: h cols [32w, 32w+32) ----
    const int m = lane & 15, q = lane >> 4;
    {
        float4v acc[2];
#pragma unroll
        for (int t = 0; t < 2; ++t) acc[t] = (float4v){0.f, 0.f, 0.f, 0.f};
        const ushort_t* arow_x = xb + (wrow + m) * IN_DIM + q * 8;
        const ushort_t* bbase1 = w1t + (w * 32 + m) * 256 + q * 8;
#pragma unroll
        for (int s = 0; s < 8; ++s) {
            short8 a;
            if (s < 4) {
                int byte = (m * 256 + q * 16 + s * 64) ^ ((m & 7) << 4);
                a = *(const short8*)((const char*)aggl + byte);
            } else {
                a = *(const short8*)(arow_x + (s - 4) * 32);
            }
#pragma unroll
            for (int t = 0; t < 2; ++t) {
                short8 b = *(const short8*)(bbase1 + (t * 16) * 256 + s * 32);
                acc[t] = __builtin_amdgcn_mfma_f32_16x16x32_bf16(a, b, acc[t], 0, 0, 0);
            }
        }
#pragma unroll
        for (int t = 0; t < 2; ++t) {
            int col = w * 32 + t * 16 + m;
            float bv = b1[col];
#pragma unroll
            for (int r = 0; r < 4; ++r) {
                int row = q * 4 + r;
                float v = fmaxf(acc[t][r] + bv, 0.0f);
                int byte = (row * 512 + col * 2) ^ ((row & 7) << 4);
                *(ushort_t*)((char*)hl + byte) = f2bf(v);
            }
        }
    }
    __syncthreads();

    // ---- phase 2: waves 0-3 -> P, waves 4-7 -> R ----
    {
        const int isP = (w < 4);
        const int cb = (w & 3) * 32;
        const ushort_t* wt = isP ? w2tl : w2tr;
        float4v acc2[2];
#pragma unroll
        for (int t = 0; t < 2; ++t) acc2[t] = (float4v){0.f, 0.f, 0.f, 0.f};
        const ushort_t* bbase2 = wt + (cb + m) * 256 + q * 8;
#pragma unroll
        for (int s = 0; s < 8; ++s) {
            int byte = (m * 512 + q * 16 + s * 64) ^ ((m & 7) << 4);
            short8 a = *(const short8*)((const char*)hl + byte);
#pragma unroll
            for (int t = 0; t < 2; ++t) {
                short8 b = *(const short8*)(bbase2 + (t * 16) * 256 + s * 32);
                acc2[t] = __builtin_amdgcn_mfma_f32_16x16x32_bf16(a, b, acc2[t], 0, 0, 0);
            }
        }
        if (isP) {
#pragma unroll
            for (int t = 0; t < 2; ++t) {
                int col = cb + t * 16 + m;
#pragma unroll
                for (int r = 0; r < 4; ++r)
                    Pb[(wrow + q * 4 + r) * OUT_DIM + col] = f2bf(acc2[t][r]);
            }
        } else {
#pragma unroll
            for (int t = 0; t < 2; ++t) {
                int col = cb + t * 16 + m;
#pragma unroll
                for (int r = 0; r < 4; ++r)
                    Rf[(wrow + q * 4 + r) * OUT_DIM + col] = acc2[t][r];
            }
        }
    }
}

// ---------------------------------------------------------------------------
// K3: final gather + epilogue: out[n][:] = mean_e P[esrc[e]][:] + R[n][:] + b2
// One 64-thread block per node; idx staged in LDS, padded to x16 with ZROW
// sentinels; 4-deep tail-free main loop.
// ---------------------------------------------------------------------------
__global__ void gather_final(const ushort_t* __restrict__ Pb,
                             const int* __restrict__ degp,
                             const ushort_t* __restrict__ esrc2,
                             const float* __restrict__ Rf,
                             const float* __restrict__ b2,
                             float* __restrict__ out) {
    __shared__ alignas(16) ushort_t sidx[MAXDEG];
    const uint4* f = (const uint4*)Pb;            // 16 uint4 per row
    const int n = blockIdx.x;
    const int g = threadIdx.x >> 4;
    const int c = threadIdx.x & 15;
    const int deg = min(degp[n], MAXDEG);
    const int pad = (deg + 15) & ~15;

    if (threadIdx.x < 16)
        ((uint4*)sidx)[threadIdx.x] = ((const uint4*)(esrc2 + n * MAXDEG))[threadIdx.x];
    __syncthreads();
    if (threadIdx.x < pad - deg) sidx[deg + threadIdx.x] = (ushort_t)ZROW;
    __syncthreads();

    float a0=0,a1=0,a2=0,a3=0,a4=0,a5=0,a6=0,a7=0;
    for (int e = g; e < pad; e += 16) {           // 4 rows in flight, no tail
        uint4 u0 = f[(int)sidx[e]      * 16 + c];
        uint4 u1 = f[(int)sidx[e + 4]  * 16 + c];
        uint4 u2 = f[(int)sidx[e + 8]  * 16 + c];
        uint4 u3 = f[(int)sidx[e + 12] * 16 + c];
        a0 += bf_lo(u0.x) + bf_lo(u1.x) + bf_lo(u2.x) + bf_lo(u3.x);
        a1 += bf_hi(u0.x) + bf_hi(u1.x) + bf_hi(u2.x) + bf_hi(u3.x);
        a2 += bf_lo(u0.y) + bf_lo(u1.y) + bf_lo(u2.y) + bf_lo(u3.y);
        a3 += bf_hi(u0.y) + bf_hi(u1.y) + bf_hi(u2.y) + bf_hi(u3.y);
        a4 += bf_lo(u0.z) + bf_lo(u1.z) + bf_lo(u2.z) + bf_lo(u3.z);
        a5 += bf_hi(u0.z) + bf_hi(u1.z) + bf_hi(u2.z) + bf_hi(u3.z);
        a6 += bf_lo(u0.w) + bf_lo(u1.w) + bf_lo(u2.w) + bf_lo(u3.w);
        a7 += bf_hi(u0.w) + bf_hi(u1.w) + bf_hi(u2.w) + bf_hi(u3.w);
    }
#pragma unroll
    for (int off = 32; off >= 16; off >>= 1) {
        a0 += __shfl_down(a0, off); a1 += __shfl_down(a1, off);
        a2 += __shfl_down(a2, off); a3 += __shfl_down(a3, off);
        a4 += __shfl_down(a4, off); a5 += __shfl_down(a5, off);
        a6 += __shfl_down(a6, off); a7 += __shfl_down(a7, off);
    }
    if (g == 0) {
        const float dinv = (deg > 0) ? 1.0f / (float)deg : 0.0f;
        const int base = n * OUT_DIM + c * 8;
        float4 r0 = *(const float4*)(Rf + base);
        float4 r1 = *(const float4*)(Rf + base + 4);
        float4 o0, o1;
        o0.x = a0 * dinv + r0.x + b2[c * 8 + 0];
        o0.y = a1 * dinv + r0.y + b2[c * 8 + 1];
        o0.z = a2 * dinv + r0.z + b2[c * 8 + 2];
        o0.w = a3 * dinv + r0.w + b2[c * 8 + 3];
        o1.x = a4 * dinv + r1.x + b2[c * 8 + 4];
        o1.y = a5 * dinv + r1.y + b2[c * 8 + 5];
        o1.z = a6 * dinv + r1.z + b2[c * 8 + 6];
        o1.w = a7 * dinv + r1.w + b2[c * 8 + 7];
        *(float4*)(out + base)     = o0;
        *(float4*)(out + base + 4) = o1;
    }
}

// ---------------------------------------------------------------------------
// Launch: memset (cnt, needed for atomic slot reservation) + 3 kernels.
// ---------------------------------------------------------------------------
extern "C" void kernel_launch(void* const* d_in, const int* in_sizes, int n_in,
                              void* d_out, int out_size, void* d_ws, size_t ws_size,
                              hipStream_t stream) {
    const float* x    = (const float*)d_in[0];
    const int*   ei   = (const int*)  d_in[1];
    const float* W1_l = (const float*)d_in[2];
    const float* b1   = (const float*)d_in[3];
    const float* W1_r = (const float*)d_in[4];
    const float* W2_l = (const float*)d_in[5];
    const float* b2   = (const float*)d_in[6];
    const float* W2_r = (const float*)d_in[7];
    float* out = (float*)d_out;

    // ---- workspace layout (byte offsets, all 16 B-aligned) ----
    // xb and Pb carry one extra zero row (ZROW = 10000) for sentinel padding.
    char* w = (char*)d_ws;
    int*      cnt   = (int*)     (w + 0);          //    40,000 B (reserve 64 KB)
    ushort_t* esrc2 = (ushort_t*)(w + 65536);      // 2,560,000 B
    ushort_t* xb    = (ushort_t*)(w + 2625536);    // 2,560,256 B (10001 rows)
    ushort_t* Pb    = (ushort_t*)(w + 5185792);    // 2,560,256 B (10001 rows)
    ushort_t* w1t   = (ushort_t*)(w + 7746048);    //   131,072 B
    ushort_t* w2tl  = (ushort_t*)(w + 7877120);    //    65,536 B
    ushort_t* w2tr  = (ushort_t*)(w + 7942656);    //    65,536 B
    float*    Rf    = (float*)   (w + 8008192);    // 5,120,000 B -> ends 13,128,192

    hipMemsetAsync(cnt, 0, N_NODES * sizeof(int), stream);

    bin_prep<<<BIN_BLOCKS + PREP_BLOCKS, K1_THREADS, 0, stream>>>(
        x, ei, W1_l, W1_r, W2_l, W2_r, xb, w1t, w2tl, w2tr, cnt, esrc2, Pb);
    gather_gemm<<<625, 512, 0, stream>>>(xb, cnt, esrc2, w1t, b1, w2tl, w2tr, Pb, Rf);
    gather_final<<<N_NODES, 64, 0, stream>>>(Pb, cnt, esrc2, Rf, b2, out);
}